// Round 15
// baseline (85.727 us; speedup 1.0000x reference)
//
#include <hip/hip_runtime.h>
#include <hip/hip_bf16.h>

#define EPSF 1e-8f

typedef short bf16x8 __attribute__((ext_vector_type(8)));
typedef float f32x4 __attribute__((ext_vector_type(4)));

// Workspace:
//   Bpk  [loc=8192][lane=64][8 u32]  bf16-packed D-fragment order (16 MiB)
//   pm0/ps0, pm1/ps1/pt1 [1024][32] ; sm*/siz*/entp [256] ; wg u16[3712]
// 6 launches: prep, ph0, comb, ph1, comb(+ent partials), ph2(+ent finalize).

__device__ __forceinline__ float bflo(unsigned u){ return __uint_as_float(u<<16); }
__device__ __forceinline__ float bfhi(unsigned u){ return __uint_as_float(u&0xffff0000u); }
__device__ __forceinline__ float bfu16(unsigned short u){ return __uint_as_float((unsigned)u<<16); }
__device__ __forceinline__ unsigned bfpack2(float a,float b){
    return (__float_as_uint(a)>>16)|(__float_as_uint(b)&0xffff0000u);
}
__device__ __forceinline__ unsigned short bfr16(float a){
    return (unsigned short)(__float_as_uint(a)>>16);
}
__device__ __forceinline__ float fastrcp(float x){ return __builtin_amdgcn_rcpf(x); }
__device__ __forceinline__ bf16x8 pack8(const float* v){
    union { unsigned u[4]; bf16x8 v8; } cv;
#pragma unroll
    for (int j = 0; j < 4; ++j) cv.u[j] = bfpack2(v[2*j], v[2*j+1]);
    return cv.v8;
}

// ---------------------------------------------------------------------------
// Prep (once): cw f32[128][27] -> wg bf16 in [k][c] wLT layout (pitch 132).
__global__ __launch_bounds__(256) void k_prep(const float* __restrict__ cw,
                                              unsigned short* __restrict__ wg) {
    const int t = threadIdx.x;
    for (int j = t; j < 3456; j += 256) {
        const int c = j / 27, k = j - c * 27;
        wg[k * 132 + c] = bfr16(cw[j]);
    }
}

// ===========================================================================
// One routing iteration from taps. PHASE 0: taps->B1+stats0p. PHASE 1:
// B1->B2+stats1p. PHASE 2: B2->out (+entropy finalize, block 0).
// Block = (b,h,8 w's), 8 waves (512 thr), wave = 1 loc. Grid 1024.
//
// LDS map (39808 B -> 4 blocks/CU = 32 waves/CU, the HW max):
//   0      slabB u16[288][12]  (taps bf16, cols = x(w0-2..w0+9))      6912
//   6912   wLT  u16[28][132]  (uint4-copied from wg)                  7424
//   14336  cbL  f32[128]
//   14848  smL f32[32] ; 14976 sizL f32[32] ; 15104 ktab u32[32]
//   15232  per-wave[8] x 3072: {Bu u32[32][20]=2560; shL f32[128]=512}
//          statb(384B)+auxL(128B) alias shL (dead by their write time;
//          ph2 returns before stats; ws/cbs shL reads precede auxL write)
// ===========================================================================
template<int PHASE>
__global__ __launch_bounds__(512, 8) void k_caps(
    const float* __restrict__ in, const unsigned short* __restrict__ wg,
    const float* __restrict__ cb, unsigned* __restrict__ Bpk,
    const float* __restrict__ sm_in, const float* __restrict__ siz_in,
    float* __restrict__ pm, float* __restrict__ ps, float* __restrict__ pt,
    float* __restrict__ outp) {
    __shared__ __align__(16) unsigned char smem[39808];
    unsigned short* slabB = (unsigned short*)smem;       // [288][12] bf16
    unsigned short* wLT = (unsigned short*)(smem + 6912);
    float* cbL  = (float*)(smem + 14336);
    float* smL  = (float*)(smem + 14848);
    float* sizL = (float*)(smem + 14976);
    unsigned* ktab = (unsigned*)(smem + 15104);

    const int t = threadIdx.x;
    const int lane = t & 63, wid = t >> 6;               // 8 waves
    const int bid = blockIdx.x;
    const int bh = bid >> 2, b = bid >> 7, h = bh & 31;
    const int w0 = (bid & 3) << 3;
    const int l15 = lane & 15, lq = lane >> 4;

    unsigned char* wb = smem + 15232 + (size_t)wid * 3072;
    unsigned* Bu  = (unsigned*)wb;                      // [32][20] bf16 pairs
    float* shL    = (float*)(wb + 2560);
    float* statb  = (float*)(wb + 2560);                // alias shL[0..95]
    float* auxL   = (float*)(wb + 2944);                // alias shL[96..127]

    // ---- prologue: slab (f32->bf16, keep cols x=w0-2..w0+9) + consts -------
    for (int j = t; j < 1152; j += 512) {
        const int r = j >> 2, q = j & 3;
        const int ci2 = r / 9, rem = r - ci2 * 9, kd = rem / 3, dy = rem - kd * 3;
        const int y = h + dy - 1;
        const int x0 = w0 - 4 + q * 4;
        float4 f = {0.f, 0.f, 0.f, 0.f};
        if ((unsigned)y < 32u && (unsigned)x0 < 32u)
            f = *reinterpret_cast<const float4*>(
                in + (((size_t)(b * 32 + ci2) * 8 + kd) * 32 + y) * 32 + x0);
        unsigned* sp = (unsigned*)slabB + r * 6;        // row = 6 u32 (12 bf16)
        if (q == 0)      sp[0] = bfpack2(f.z, f.w);               // w0-2,w0-1
        else if (q == 1) { sp[1] = bfpack2(f.x, f.y);             // w0..w0+3
                           sp[2] = bfpack2(f.z, f.w); }
        else if (q == 2) { sp[3] = bfpack2(f.x, f.y);             // w0+4..w0+7
                           sp[4] = bfpack2(f.z, f.w); }
        else             sp[5] = bfpack2(f.x, f.y);               // w0+8,w0+9
    }
    {
        const uint4* wg4 = (const uint4*)wg;
        uint4* wl4 = (uint4*)wLT;
        for (int j = t; j < 464; j += 512) wl4[j] = wg4[j];
    }
    if (t < 128) cbL[t] = cb[t];
    if (t < 32) {
        const int k = t < 27 ? t : 26;      // clamped; kt>=27 masked at use
        const int kd = k / 9, r9 = k - kd * 9, dy = r9 / 3, dx = r9 - dy * 3;
        ktab[t] = (unsigned)((kd * 3 + dy) * 12 + dx);
    }
    if constexpr (PHASE >= 1) {
        if (t < 32) { smL[t] = sm_in[b * 32 + t]; sizL[t] = siz_in[b * 32 + t]; }
    }
    __syncthreads();

    const size_t loc = (size_t)bh * 32 + w0 + wid;
    const int tb = wid + 1;                 // tap col base (x = w0+wid-1)

    float b1v[16];
    if constexpr (PHASE == 0) {
        // vsum[k] = sum_ci v[ci][k]  (iter0 uniform-k identity)
        const int k2 = lane >> 1, half = lane & 1;
        float vs = 0.f;
        if (k2 < 27) {
            const unsigned short* sp = slabB + half * 1728 + ktab[k2] + tb;
#pragma unroll
            for (int i = 0; i < 16; ++i) vs += bfu16(sp[i * 108]);
        }
        vs += __shfl_xor(vs, 1);
        if (half == 0 && k2 < 27) auxL[k2] = vs;
    } else {
        // load previous B (bf16, D-frag order), stage into Bu as ci-pairs
        const uint4* Bg = (const uint4*)(Bpk + loc * 512 + (size_t)lane * 8);
        const uint4 q0 = Bg[0], q1 = Bg[1];
        const unsigned pk[8] = {q0.x, q0.y, q0.z, q0.w, q1.x, q1.y, q1.z, q1.w};
#pragma unroll
        for (int e = 0; e < 8; ++e) { b1v[2*e] = bflo(pk[e]); b1v[2*e+1] = bfhi(pk[e]); }
#pragma unroll
        for (int mt = 0; mt < 2; ++mt)
#pragma unroll
        for (int reg = 0; reg < 4; ++reg)
#pragma unroll
        for (int nt = 0; nt < 2; ++nt) {
            const float me = b1v[mt*8 + nt*4 + reg];
            const float ot = __shfl_xor(me, 1);
            const unsigned pku = (l15 & 1) ? bfpack2(ot, me) : bfpack2(me, ot);
            if ((l15 & 1) == nt)
                Bu[(mt*16 + lq*4 + reg)*20 + nt*8 + (l15 >> 1)] = pku;
        }
        // kmat A-frags: row cj = mt*16+l15, k(ci) = lq*8+j
        bf16x8 kmA[2];
#pragma unroll
        for (int mt = 0; mt < 2; ++mt) {
            const uint4 q = *(const uint4*)(Bu + (mt*16 + l15)*20 + lq*4);
            const unsigned uu[4] = {q.x, q.y, q.z, q.w};
            float ev[8];
#pragma unroll
            for (int j2 = 0; j2 < 4; ++j2) {
                const int ci0 = lq*8 + 2*j2;
                ev[2*j2]   = __expf(bflo(uu[j2]) - smL[ci0])   * sizL[ci0];
                ev[2*j2+1] = __expf(bfhi(uu[j2]) - smL[ci0+1]) * sizL[ci0+1];
            }
            kmA[mt] = pack8(ev);
        }
        // vT B-frags: col kt = nt*16+l15, k(ci) = lq*8+j; kt==27 -> ones col
        bf16x8 vtB[2];
#pragma unroll
        for (int nt = 0; nt < 2; ++nt) {
            const int kt = nt*16 + l15;
            const unsigned ko = ktab[kt];
            union { unsigned short s[8]; bf16x8 v8; } cv;
#pragma unroll
            for (int j = 0; j < 8; ++j) {
                const unsigned short sv = slabB[(lq*8 + j)*108 + ko + tb];
                cv.s[j] = (kt < 27) ? sv : (unsigned short)(kt == 27 ? 0x3f80 : 0);
            }
            vtB[nt] = cv.v8;
        }
        // matmul1: u[cj][kt] = kmat x vT ; store to Bu as kt-pairs
        f32x4 accu[2][2];
#pragma unroll
        for (int mt = 0; mt < 2; ++mt)
#pragma unroll
        for (int nt = 0; nt < 2; ++nt)
            accu[mt][nt] = __builtin_amdgcn_mfma_f32_16x16x32_bf16(
                kmA[mt], vtB[nt], (f32x4){0.f,0.f,0.f,0.f}, 0, 0, 0);
#pragma unroll
        for (int mt = 0; mt < 2; ++mt)
#pragma unroll
        for (int reg = 0; reg < 4; ++reg)
#pragma unroll
        for (int nt = 0; nt < 2; ++nt) {
            const float me = accu[mt][nt][reg];
            const float ot = __shfl_xor(me, 1);
            const unsigned pku = (l15 & 1) ? bfpack2(ot, me) : bfpack2(me, ot);
            if ((l15 & 1) == nt)
                Bu[(mt*16 + lq*4 + reg)*20 + nt*8 + (l15 >> 1)] = pku;
        }
    }

    // ---- S + squash (c = lane, lane+64) ------------------------------------
#pragma unroll
    for (int cc = 0; cc < 2; ++cc) {
        const int c = lane + cc * 64;
        float S;
        if constexpr (PHASE == 0) {
            S = 0.f;
#pragma unroll
            for (int k = 0; k < 27; ++k)
                S = fmaf(bfu16(wLT[k*132 + c]), auxL[k], S);
            S = S * (1.0f/32768.0f) + cbL[c] * (1.0f/1024.0f);
        } else {
            const unsigned* up = Bu + (c >> 2) * 20;
            S = 0.f;
#pragma unroll
            for (int p = 0; p < 13; ++p) {
                const unsigned u = up[p];
                S = fmaf(bfu16(wLT[(2*p)*132 + c]),   bflo(u), S);
                S = fmaf(bfu16(wLT[(2*p+1)*132 + c]), bfhi(u), S);
            }
            const unsigned u13 = up[13];
            S = fmaf(bfu16(wLT[26*132 + c]), bflo(u13), S);
            S = fmaf(cbL[c], bfhi(u13), S);        // + cb * K1[cj]
        }
        const float sq = fabsf(S) * S * fastrcp(1.f + S*S + EPSF);
        shL[c] = sq;
    }

    if constexpr (PHASE == 2) {
        // epilogue: gather 8 waves' shL -> out [b][c][h][w0..w0+7]
        __syncthreads();
        if (t < 256) {
            const int c = t >> 1, half = t & 1;
            float o[4];
#pragma unroll
            for (int j = 0; j < 4; ++j) {
                const int w = half * 4 + j;
                o[j] = ((const float*)(smem + 15232 + w * 3072 + 2560))[c];
            }
            *reinterpret_cast<float4*>(
                outp + ((size_t)(b*128 + c))*1024 + (size_t)h*32 + w0 + half*4) =
                make_float4(o[0], o[1], o[2], o[3]);
        }
        if (bid == 0) {        // entropy finalize from entp partials (pt arg)
            float* er = (float*)smem;    // slab dead
            if (t < 256) er[t] = pt[t];
            __syncthreads();
            for (int s2v = 128; s2v > 0; s2v >>= 1) {
                if (t < s2v) er[t] += er[t + s2v];
                __syncthreads();
            }
            if (t == 0) outp[1048576] = er[0] * (1.0f/256.0f);
        }
        return;
    }

    // ---- ws = sum_nj sh*w (bf16, overlays Bu) ; cbs -> auxL ----------------
    {
        const int k0 = 2*l15, k1 = k0 + 1;
#pragma unroll
        for (int i = 0; i < 8; ++i) {
            const int cj = lq + 4*i;
            float v0 = 0.f, v1 = 0.f;
            if (k0 < 27) {
#pragma unroll
                for (int nj = 0; nj < 4; ++nj)
                    v0 = fmaf(shL[cj*4+nj], bfu16(wLT[k0*132 + cj*4 + nj]), v0);
            }
            if (k1 < 27) {
#pragma unroll
                for (int nj = 0; nj < 4; ++nj)
                    v1 = fmaf(shL[cj*4+nj], bfu16(wLT[k1*132 + cj*4 + nj]), v1);
            }
            Bu[cj*20 + l15] = bfpack2(v0, v1);
        }
        if (lane < 32) {
            float cv = 0.f;
#pragma unroll
            for (int nj = 0; nj < 4; ++nj)
                cv = fmaf(shL[lane*4+nj], cbL[lane*4+nj], cv);
            auxL[lane] = cv;               // aliases shL[96..127], now dead
        }
    }

    // ---- matmul2: B_upd = ws x v -------------------------------------------
    bf16x8 wsA[2], vB[2];
#pragma unroll
    for (int mt = 0; mt < 2; ++mt) {
        union { uint4 q4; bf16x8 v8; } cv;
        cv.q4 = *(const uint4*)(Bu + (mt*16 + l15)*20 + lq*4);
        wsA[mt] = cv.v8;
    }
#pragma unroll
    for (int nt = 0; nt < 2; ++nt) {
        const int ci = nt*16 + l15;
        union { unsigned short s[8]; bf16x8 v8; } cv;
#pragma unroll
        for (int j = 0; j < 8; ++j) {
            const int k = lq*8 + j;
            const unsigned short sv = slabB[ci*108 + ktab[k] + tb];
            cv.s[j] = (k < 27) ? sv : (unsigned short)0;
        }
        vB[nt] = cv.v8;
    }
    f32x4 accb[2][2];
#pragma unroll
    for (int mt = 0; mt < 2; ++mt)
#pragma unroll
    for (int nt = 0; nt < 2; ++nt)
        accb[mt][nt] = __builtin_amdgcn_mfma_f32_16x16x32_bf16(
            wsA[mt], vB[nt], (f32x4){0.f,0.f,0.f,0.f}, 0, 0, 0);

    // ---- B_new = [B_prev +] upd + cbs ; pack ; store ; stats ---------------
    float bnew[16];
#pragma unroll
    for (int mt = 0; mt < 2; ++mt)
#pragma unroll
    for (int nt = 0; nt < 2; ++nt)
#pragma unroll
    for (int reg = 0; reg < 4; ++reg) {
        float val = accb[mt][nt][reg] + auxL[mt*16 + lq*4 + reg];
        if constexpr (PHASE == 1) val += b1v[mt*8 + nt*4 + reg];
        bnew[mt*8 + nt*4 + reg] = val;
    }
    {
        unsigned pk[8];
#pragma unroll
        for (int e = 0; e < 8; ++e) pk[e] = bfpack2(bnew[2*e], bnew[2*e+1]);
        uint4* Bg = (uint4*)(Bpk + loc * 512 + (size_t)lane * 8);
        Bg[0] = make_uint4(pk[0], pk[1], pk[2], pk[3]);
        Bg[1] = make_uint4(pk[4], pk[5], pk[6], pk[7]);
    }
    float m2[2], s2[2], T2[2];
#pragma unroll
    for (int nt = 0; nt < 2; ++nt) {
        float m = -1e30f;
#pragma unroll
        for (int mt = 0; mt < 2; ++mt)
#pragma unroll
        for (int reg = 0; reg < 4; ++reg) m = fmaxf(m, bnew[mt*8 + nt*4 + reg]);
        float s = 0.f, T = 0.f;
#pragma unroll
        for (int mt = 0; mt < 2; ++mt)
#pragma unroll
        for (int reg = 0; reg < 4; ++reg) {
            const float d = bnew[mt*8 + nt*4 + reg] - m;
            const float e = __expf(d);
            s += e; T += e * d;
        }
        m2[nt] = m; s2[nt] = s; T2[nt] = T;
#pragma unroll
        for (int off = 16; off <= 32; off <<= 1) {   // lanes ^16,^32 share ci
            const float mo = __shfl_xor(m2[nt], off);
            const float so = __shfl_xor(s2[nt], off);
            const float To = __shfl_xor(T2[nt], off);
            const float nm = fmaxf(m2[nt], mo);
            const float ea = __expf(m2[nt]-nm), eb = __expf(mo-nm);
            T2[nt] = ea*(T2[nt] + s2[nt]*(m2[nt]-nm)) + eb*(To + so*(mo-nm));
            s2[nt] = ea*s2[nt] + eb*so;
            m2[nt] = nm;
        }
    }
    if (lane < 16) {                     // statb aliases shL[0..95] (dead here)
#pragma unroll
        for (int nt = 0; nt < 2; ++nt) {
            const int ci = nt*16 + lane;
            statb[ci] = m2[nt]; statb[32+ci] = s2[nt]; statb[64+ci] = T2[nt];
        }
    }
    __syncthreads();
    if (t < 32) {            // merge 8 waves -> block partial
        float M = -1e30f, Z = 0.f, T = 0.f;
#pragma unroll
        for (int wv = 0; wv < 8; ++wv) {
            const float* sw = (const float*)(smem + 15232 + wv*3072 + 2560);
            const float mo = sw[t], so = sw[32+t], To = sw[64+t];
            const float nm = fmaxf(M, mo);
            const float ea = __expf(M-nm), eb = __expf(mo-nm);
            T = ea*(T + Z*(M-nm)) + eb*(To + so*(mo-nm));
            Z = ea*Z + eb*so;
            M = nm;
        }
        pm[bid*32 + t] = M;
        ps[bid*32 + t] = Z;
        if constexpr (PHASE == 1) pt[bid*32 + t] = T;
    }
}

// ---------------------------------------------------------------------------
// Combine NPART partials per (b,ci) -> sm, siz (+ entropy partial if ENT).
template <int NPART, bool ENT>
__global__ __launch_bounds__(256) void k_comb(const float* __restrict__ pm,
                                              const float* __restrict__ ps,
                                              const float* __restrict__ pt,
                                              float* __restrict__ sm,
                                              float* __restrict__ siz,
                                              float* __restrict__ entp) {
    const int b = blockIdx.x, t = threadIdx.x;
    const int ci = t & 31, seg = t >> 5;
    constexpr int PER = NPART / 8;
    __shared__ float red[3][8][33];

    float M = -1e30f;
    for (int k = 0; k < PER; ++k)
        M = fmaxf(M, pm[((size_t)b * NPART + seg * PER + k) * 32 + ci]);
    red[0][seg][ci] = M;
    __syncthreads();
    float Mg = red[0][0][ci];
#pragma unroll
    for (int q = 1; q < 8; ++q) Mg = fmaxf(Mg, red[0][q][ci]);

    float Z = 0.0f, T = 0.0f;
    for (int k = 0; k < PER; ++k) {
        const size_t i = ((size_t)b * NPART + seg * PER + k) * 32 + ci;
        const float dm = pm[i] - Mg;
        const float e = __expf(dm);
        Z += ps[i] * e;
        if constexpr (ENT) T += (pt[i] + ps[i] * dm) * e;
    }
    red[1][seg][ci] = Z;
    if constexpr (ENT) red[2][seg][ci] = T;
    __syncthreads();
    if (t < 32) {
        float Zt = 0.0f, Tt = 0.0f;
#pragma unroll
        for (int q = 0; q < 8; ++q) {
            Zt += red[1][q][ci];
            if constexpr (ENT) Tt += red[2][q][ci];
        }
        sm[b * 32 + ci] = Mg;
        siz[b * 32 + ci] = 1.0f / Zt;
        if constexpr (ENT)   // ent = (lnZ - T/Z)/ln(32768); eps-in-log ~3e-5
            entp[b * 32 + ci] = (logf(Zt) - Tt / Zt) * (1.0f / 10.39720770839918f);
    }
}

// ---------------------------------------------------------------------------
extern "C" void kernel_launch(void* const* d_in, const int* in_sizes, int n_in,
                              void* d_out, int out_size, void* d_ws, size_t ws_size,
                              hipStream_t stream) {
    const float* in = (const float*)d_in[0];   // (8,32,8,32,32)
    const float* cw = (const float*)d_in[1];   // (128,1,3,3,3)
    const float* cb = (const float*)d_in[2];   // (128,)
    float* out = (float*)d_out;                // 1048576 + 1 floats

    unsigned* Bpk = (unsigned*)d_ws;           // 16 MiB
    float* pm0  = (float*)(Bpk + 4194304);     // [1024*32] each
    float* ps0  = pm0 + 32768;
    float* pm1  = ps0 + 32768;
    float* ps1  = pm1 + 32768;
    float* pt1  = ps1 + 32768;
    float* sm0  = pt1 + 32768;                 // [256] each
    float* siz0 = sm0 + 256;
    float* sm1  = siz0 + 256;
    float* siz1 = sm1 + 256;
    float* entp = siz1 + 256;
    unsigned short* wg = (unsigned short*)(entp + 256);   // 3712 u16

    k_prep<<<1, 256, 0, stream>>>(cw, wg);
    k_caps<0><<<1024, 512, 0, stream>>>(in, wg, cb, Bpk,
                                        nullptr, nullptr, pm0, ps0, pt1, out);
    k_comb<128, false><<<8, 256, 0, stream>>>(pm0, ps0, nullptr, sm0, siz0, nullptr);
    k_caps<1><<<1024, 512, 0, stream>>>(in, wg, cb, Bpk,
                                        sm0, siz0, pm1, ps1, pt1, out);
    k_comb<128, true><<<8, 256, 0, stream>>>(pm1, ps1, pt1, sm1, siz1, entp);
    k_caps<2><<<1024, 512, 0, stream>>>(in, wg, cb, Bpk,
                                        sm1, siz1, pm1, ps1, entp, out);
}

// Round 16
// 81.231 us; speedup vs baseline: 1.0553x; 1.0553x over previous
//
#include <hip/hip_runtime.h>
#include <hip/hip_bf16.h>

#define EPSF 1e-8f

typedef short bf16x8 __attribute__((ext_vector_type(8)));
typedef float f32x4 __attribute__((ext_vector_type(4)));

// Workspace:
//   Bpk  [loc=8192][lane=64][8 u32]  bf16-packed D-fragment order (16 MiB)
//   pm0/ps0, pm1/ps1/pt1 [2048][32] ; sm*/siz*/entp [256] ; wg u16[3712]
// 5 launches: ph0 (converts weights, publishes wg), comb, ph1, comb(+ent
// partials), ph2(+ent finalize).

__device__ __forceinline__ float bflo(unsigned u){ return __uint_as_float(u<<16); }
__device__ __forceinline__ float bfhi(unsigned u){ return __uint_as_float(u&0xffff0000u); }
__device__ __forceinline__ float bfu16(unsigned short u){ return __uint_as_float((unsigned)u<<16); }
__device__ __forceinline__ unsigned bfpack2(float a,float b){
    return (__float_as_uint(a)>>16)|(__float_as_uint(b)&0xffff0000u);
}
__device__ __forceinline__ unsigned short bfr16(float a){
    return (unsigned short)(__float_as_uint(a)>>16);
}
__device__ __forceinline__ float fastrcp(float x){ return __builtin_amdgcn_rcpf(x); }
__device__ __forceinline__ bf16x8 pack8(const float* v){
    union { unsigned u[4]; bf16x8 v8; } cv;
#pragma unroll
    for (int j = 0; j < 4; ++j) cv.u[j] = bfpack2(v[2*j], v[2*j+1]);
    return cv.v8;
}

// ===========================================================================
// One routing iteration from taps. PHASE 0: taps->B1+stats0p (also converts
// cw->wLT in-block and block 0 publishes wg). PHASE 1: B1->B2+stats1p.
// PHASE 2: B2->out (+entropy finalize, block 0).
// Block = (b,h,4 w's), 4 waves, wave = 1 loc. Grid 2048.
//
// LDS map (25728 B -> 6 blocks/CU = 24 waves/CU):
//   0      slabB u16[288][8]  (taps bf16, cols = global w0-2..w0+5)   4608
//   4608   wLT  u16[28][132]  (ph0: converted from cw; ph1/2: from wg) 7424
//   12032  cbL  f32[128]
//   12544  smL f32[32] ; 12672 sizL f32[32] ; 12800 ktab u32[32]
//   12928  per-wave[4] x 3200: {Bu u32[32][20]=2560; shL f32[128]=512;
//                               auxL f32[32]=128}; statb aliases shL
// ===========================================================================
template<int PHASE>
__global__ __launch_bounds__(256, 6) void k_caps(
    const float* __restrict__ in, const float* __restrict__ cw,
    unsigned short* __restrict__ wg,
    const float* __restrict__ cb, unsigned* __restrict__ Bpk,
    const float* __restrict__ sm_in, const float* __restrict__ siz_in,
    float* __restrict__ pm, float* __restrict__ ps, float* __restrict__ pt,
    float* __restrict__ outp) {
    __shared__ __align__(16) unsigned char smem[25728];
    unsigned short* slabB = (unsigned short*)smem;       // [288][8] bf16
    unsigned short* wLT = (unsigned short*)(smem + 4608);
    float* cbL  = (float*)(smem + 12032);
    float* smL  = (float*)(smem + 12544);
    float* sizL = (float*)(smem + 12672);
    unsigned* ktab = (unsigned*)(smem + 12800);

    const int t = threadIdx.x;
    const int lane = t & 63, wid = t >> 6;
    const int bid = blockIdx.x;
    const int bh = bid >> 3, b = bh >> 5, h = bh & 31;
    const int w0 = (bid & 7) << 2;
    const int l15 = lane & 15, lq = lane >> 4;

    unsigned char* wb = smem + 12928 + (size_t)wid * 3200;
    unsigned* Bu  = (unsigned*)wb;                      // [32][20] bf16 pairs
    float* shL    = (float*)(wb + 2560);
    float* auxL   = (float*)(wb + 3072);
    float* statb  = (float*)(wb + 2560);                // alias shL

    // ---- prologue: slab (f32->bf16, keep cols 2..9) + weights + consts ----
    for (int j = t; j < 864; j += 256) {
        const int r = j / 3, q = j - r * 3;
        const int ci2 = r / 9, rem = r - ci2 * 9, kd = rem / 3, dy = rem - kd * 3;
        const int y = h + dy - 1;
        const int x0 = w0 - 4 + q * 4;
        float4 f = {0.f, 0.f, 0.f, 0.f};
        if ((unsigned)y < 32u && (unsigned)x0 < 32u)
            f = *reinterpret_cast<const float4*>(
                in + (((size_t)(b * 32 + ci2) * 8 + kd) * 32 + y) * 32 + x0);
        unsigned* sp = (unsigned*)slabB + r * 4;        // row = 4 u32 (8 bf16)
        if (q == 0)      sp[0] = bfpack2(f.z, f.w);               // x = w0-2,w0-1
        else if (q == 1) { sp[1] = bfpack2(f.x, f.y);             // w0, w0+1
                           sp[2] = bfpack2(f.z, f.w); }           // w0+2, w0+3
        else             sp[3] = bfpack2(f.x, f.y);               // w0+4, w0+5
    }
    if constexpr (PHASE == 0) {
        for (int j = t; j < 3456; j += 256) {
            const int c = j / 27, k = j - c * 27;
            wLT[k * 132 + c] = bfr16(cw[j]);
        }
    } else {
        const uint4* wg4 = (const uint4*)wg;
        uint4* wl4 = (uint4*)wLT;
        for (int j = t; j < 464; j += 256) wl4[j] = wg4[j];
    }
    if (t < 128) cbL[t] = cb[t];
    if (t < 32) {
        const int k = t < 27 ? t : 26;      // clamped; kt>=27 masked at use
        const int kd = k / 9, r9 = k - kd * 9, dy = r9 / 3, dx = r9 - dy * 3;
        ktab[t] = (unsigned)((kd * 3 + dy) * 8 + dx);
    }
    if constexpr (PHASE >= 1) {
        if (t < 32) { smL[t] = sm_in[b * 32 + t]; sizL[t] = siz_in[b * 32 + t]; }
    }
    __syncthreads();

    if constexpr (PHASE == 0) {
        if (bid == 0) {                      // publish converted table
            const uint4* wl4 = (const uint4*)wLT;
            uint4* wg4 = (uint4*)wg;
            for (int j = t; j < 464; j += 256) wg4[j] = wl4[j];
        }
    }

    const size_t loc = (size_t)bh * 32 + w0 + wid;
    const int tb = wid + 1;                 // tap col base (x = w0+wid-1 ...)

    float b1v[16];
    if constexpr (PHASE == 0) {
        // vsum[k] = sum_ci v[ci][k]  (iter0 uniform-k identity)
        const int k2 = lane >> 1, half = lane & 1;
        float vs = 0.f;
        if (k2 < 27) {
            const unsigned short* sp = slabB + half * 16 * 72 + ktab[k2] + tb;
#pragma unroll
            for (int i = 0; i < 16; ++i) vs += bfu16(sp[i * 72]);
        }
        vs += __shfl_xor(vs, 1);
        if (half == 0 && k2 < 27) auxL[k2] = vs;
    } else {
        // load previous B (bf16, D-frag order), stage into Bu as ci-pairs
        const uint4* Bg = (const uint4*)(Bpk + loc * 512 + (size_t)lane * 8);
        const uint4 q0 = Bg[0], q1 = Bg[1];
        const unsigned pk[8] = {q0.x, q0.y, q0.z, q0.w, q1.x, q1.y, q1.z, q1.w};
#pragma unroll
        for (int e = 0; e < 8; ++e) { b1v[2*e] = bflo(pk[e]); b1v[2*e+1] = bfhi(pk[e]); }
#pragma unroll
        for (int mt = 0; mt < 2; ++mt)
#pragma unroll
        for (int reg = 0; reg < 4; ++reg)
#pragma unroll
        for (int nt = 0; nt < 2; ++nt) {
            const float me = b1v[mt*8 + nt*4 + reg];
            const float ot = __shfl_xor(me, 1);
            const unsigned pku = (l15 & 1) ? bfpack2(ot, me) : bfpack2(me, ot);
            if ((l15 & 1) == nt)
                Bu[(mt*16 + lq*4 + reg)*20 + nt*8 + (l15 >> 1)] = pku;
        }
        // kmat A-frags: row cj = mt*16+l15, k(ci) = lq*8+j
        bf16x8 kmA[2];
#pragma unroll
        for (int mt = 0; mt < 2; ++mt) {
            const uint4 q = *(const uint4*)(Bu + (mt*16 + l15)*20 + lq*4);
            const unsigned uu[4] = {q.x, q.y, q.z, q.w};
            float ev[8];
#pragma unroll
            for (int j2 = 0; j2 < 4; ++j2) {
                const int ci0 = lq*8 + 2*j2;
                ev[2*j2]   = __expf(bflo(uu[j2]) - smL[ci0])   * sizL[ci0];
                ev[2*j2+1] = __expf(bfhi(uu[j2]) - smL[ci0+1]) * sizL[ci0+1];
            }
            kmA[mt] = pack8(ev);
        }
        // vT B-frags: col kt = nt*16+l15, k(ci) = lq*8+j; kt==27 -> ones col
        bf16x8 vtB[2];
#pragma unroll
        for (int nt = 0; nt < 2; ++nt) {
            const int kt = nt*16 + l15;
            const unsigned ko = ktab[kt];
            union { unsigned short s[8]; bf16x8 v8; } cv;
#pragma unroll
            for (int j = 0; j < 8; ++j) {
                const unsigned short sv = slabB[(lq*8 + j)*72 + ko + tb];
                cv.s[j] = (kt < 27) ? sv : (unsigned short)(kt == 27 ? 0x3f80 : 0);
            }
            vtB[nt] = cv.v8;
        }
        // matmul1: u[cj][kt] = kmat x vT ; store to Bu as kt-pairs
        f32x4 accu[2][2];
#pragma unroll
        for (int mt = 0; mt < 2; ++mt)
#pragma unroll
        for (int nt = 0; nt < 2; ++nt)
            accu[mt][nt] = __builtin_amdgcn_mfma_f32_16x16x32_bf16(
                kmA[mt], vtB[nt], (f32x4){0.f,0.f,0.f,0.f}, 0, 0, 0);
#pragma unroll
        for (int mt = 0; mt < 2; ++mt)
#pragma unroll
        for (int reg = 0; reg < 4; ++reg)
#pragma unroll
        for (int nt = 0; nt < 2; ++nt) {
            const float me = accu[mt][nt][reg];
            const float ot = __shfl_xor(me, 1);
            const unsigned pku = (l15 & 1) ? bfpack2(ot, me) : bfpack2(me, ot);
            if ((l15 & 1) == nt)
                Bu[(mt*16 + lq*4 + reg)*20 + nt*8 + (l15 >> 1)] = pku;
        }
    }

    // ---- S + squash (c = lane, lane+64) ------------------------------------
#pragma unroll
    for (int cc = 0; cc < 2; ++cc) {
        const int c = lane + cc * 64;
        float S;
        if constexpr (PHASE == 0) {
            S = 0.f;
#pragma unroll
            for (int k = 0; k < 27; ++k)
                S = fmaf(bfu16(wLT[k*132 + c]), auxL[k], S);
            S = S * (1.0f/32768.0f) + cbL[c] * (1.0f/1024.0f);
        } else {
            const unsigned* up = Bu + (c >> 2) * 20;
            S = 0.f;
#pragma unroll
            for (int p = 0; p < 13; ++p) {
                const unsigned u = up[p];
                S = fmaf(bfu16(wLT[(2*p)*132 + c]),   bflo(u), S);
                S = fmaf(bfu16(wLT[(2*p+1)*132 + c]), bfhi(u), S);
            }
            const unsigned u13 = up[13];
            S = fmaf(bfu16(wLT[26*132 + c]), bflo(u13), S);
            S = fmaf(cbL[c], bfhi(u13), S);        // + cb * K1[cj]
        }
        const float sq = fabsf(S) * S * fastrcp(1.f + S*S + EPSF);
        shL[c] = sq;
    }

    if constexpr (PHASE == 2) {
        // epilogue: gather 4 waves' shL -> out [b][c][h][w0..w0+3] (float4)
        __syncthreads();
        if (t < 128) {
            const float* s0 = (const float*)(smem + 12928 + 0*3200 + 2560);
            const float* s1 = (const float*)(smem + 12928 + 1*3200 + 2560);
            const float* s2 = (const float*)(smem + 12928 + 2*3200 + 2560);
            const float* s3 = (const float*)(smem + 12928 + 3*3200 + 2560);
            float4 o = make_float4(s0[t], s1[t], s2[t], s3[t]);
            *reinterpret_cast<float4*>(
                outp + ((size_t)(b*128 + t))*1024 + (size_t)h*32 + w0) = o;
        }
        if (bid == 0) {        // entropy finalize from entp partials (pt arg)
            float* er = (float*)smem;    // slab dead
            er[t] = pt[t];
            __syncthreads();
            for (int s2v = 128; s2v > 0; s2v >>= 1) {
                if (t < s2v) er[t] += er[t + s2v];
                __syncthreads();
            }
            if (t == 0) outp[1048576] = er[0] * (1.0f/256.0f);
        }
        return;
    }

    // ---- ws = sum_nj sh*w (bf16, overlays Bu) ; cbs -> auxL ----------------
    {
        const int k0 = 2*l15, k1 = k0 + 1;
#pragma unroll
        for (int i = 0; i < 8; ++i) {
            const int cj = lq + 4*i;
            float v0 = 0.f, v1 = 0.f;
            if (k0 < 27) {
#pragma unroll
                for (int nj = 0; nj < 4; ++nj)
                    v0 = fmaf(shL[cj*4+nj], bfu16(wLT[k0*132 + cj*4 + nj]), v0);
            }
            if (k1 < 27) {
#pragma unroll
                for (int nj = 0; nj < 4; ++nj)
                    v1 = fmaf(shL[cj*4+nj], bfu16(wLT[k1*132 + cj*4 + nj]), v1);
            }
            Bu[cj*20 + l15] = bfpack2(v0, v1);
        }
        if (lane < 32) {
            float cv = 0.f;
#pragma unroll
            for (int nj = 0; nj < 4; ++nj)
                cv = fmaf(shL[lane*4+nj], cbL[lane*4+nj], cv);
            auxL[lane] = cv;
        }
    }

    // ---- matmul2: B_upd = ws x v -------------------------------------------
    bf16x8 wsA[2], vB[2];
#pragma unroll
    for (int mt = 0; mt < 2; ++mt) {
        union { uint4 q4; bf16x8 v8; } cv;
        cv.q4 = *(const uint4*)(Bu + (mt*16 + l15)*20 + lq*4);
        wsA[mt] = cv.v8;
    }
#pragma unroll
    for (int nt = 0; nt < 2; ++nt) {
        const int ci = nt*16 + l15;
        union { unsigned short s[8]; bf16x8 v8; } cv;
#pragma unroll
        for (int j = 0; j < 8; ++j) {
            const int k = lq*8 + j;
            const unsigned short sv = slabB[ci*72 + ktab[k] + tb];
            cv.s[j] = (k < 27) ? sv : (unsigned short)0;
        }
        vB[nt] = cv.v8;
    }
    f32x4 accb[2][2];
#pragma unroll
    for (int mt = 0; mt < 2; ++mt)
#pragma unroll
    for (int nt = 0; nt < 2; ++nt)
        accb[mt][nt] = __builtin_amdgcn_mfma_f32_16x16x32_bf16(
            wsA[mt], vB[nt], (f32x4){0.f,0.f,0.f,0.f}, 0, 0, 0);

    // ---- B_new = [B_prev +] upd + cbs ; pack ; store ; stats ---------------
    float bnew[16];
#pragma unroll
    for (int mt = 0; mt < 2; ++mt)
#pragma unroll
    for (int nt = 0; nt < 2; ++nt)
#pragma unroll
    for (int reg = 0; reg < 4; ++reg) {
        float val = accb[mt][nt][reg] + auxL[mt*16 + lq*4 + reg];
        if constexpr (PHASE == 1) val += b1v[mt*8 + nt*4 + reg];
        bnew[mt*8 + nt*4 + reg] = val;
    }
    {
        unsigned pk[8];
#pragma unroll
        for (int e = 0; e < 8; ++e) pk[e] = bfpack2(bnew[2*e], bnew[2*e+1]);
        uint4* Bg = (uint4*)(Bpk + loc * 512 + (size_t)lane * 8);
        Bg[0] = make_uint4(pk[0], pk[1], pk[2], pk[3]);
        Bg[1] = make_uint4(pk[4], pk[5], pk[6], pk[7]);
    }
    float m2[2], s2[2], T2[2];
#pragma unroll
    for (int nt = 0; nt < 2; ++nt) {
        float m = -1e30f;
#pragma unroll
        for (int mt = 0; mt < 2; ++mt)
#pragma unroll
        for (int reg = 0; reg < 4; ++reg) m = fmaxf(m, bnew[mt*8 + nt*4 + reg]);
        float s = 0.f, T = 0.f;
#pragma unroll
        for (int mt = 0; mt < 2; ++mt)
#pragma unroll
        for (int reg = 0; reg < 4; ++reg) {
            const float d = bnew[mt*8 + nt*4 + reg] - m;
            const float e = __expf(d);
            s += e; T += e * d;
        }
        m2[nt] = m; s2[nt] = s; T2[nt] = T;
#pragma unroll
        for (int off = 16; off <= 32; off <<= 1) {   // lanes ^16,^32 share ci
            const float mo = __shfl_xor(m2[nt], off);
            const float so = __shfl_xor(s2[nt], off);
            const float To = __shfl_xor(T2[nt], off);
            const float nm = fmaxf(m2[nt], mo);
            const float ea = __expf(m2[nt]-nm), eb = __expf(mo-nm);
            T2[nt] = ea*(T2[nt] + s2[nt]*(m2[nt]-nm)) + eb*(To + so*(mo-nm));
            s2[nt] = ea*s2[nt] + eb*so;
            m2[nt] = nm;
        }
    }
    if (lane < 16) {                     // statb aliases shL (dead here)
#pragma unroll
        for (int nt = 0; nt < 2; ++nt) {
            const int ci = nt*16 + lane;
            statb[ci] = m2[nt]; statb[32+ci] = s2[nt]; statb[64+ci] = T2[nt];
        }
    }
    __syncthreads();
    if (t < 32) {            // merge 4 waves -> block partial
        float M = -1e30f, Z = 0.f, T = 0.f;
#pragma unroll
        for (int wv = 0; wv < 4; ++wv) {
            const float* sw = (const float*)(smem + 12928 + wv*3200 + 2560);
            const float mo = sw[t], so = sw[32+t], To = sw[64+t];
            const float nm = fmaxf(M, mo);
            const float ea = __expf(M-nm), eb = __expf(mo-nm);
            T = ea*(T + Z*(M-nm)) + eb*(To + so*(mo-nm));
            Z = ea*Z + eb*so;
            M = nm;
        }
        pm[bid*32 + t] = M;
        ps[bid*32 + t] = Z;
        if constexpr (PHASE == 1) pt[bid*32 + t] = T;
    }
}

// ---------------------------------------------------------------------------
// Combine NPART partials per (b,ci) -> sm, siz (+ entropy partial if ENT).
template <int NPART, bool ENT>
__global__ __launch_bounds__(256) void k_comb(const float* __restrict__ pm,
                                              const float* __restrict__ ps,
                                              const float* __restrict__ pt,
                                              float* __restrict__ sm,
                                              float* __restrict__ siz,
                                              float* __restrict__ entp) {
    const int b = blockIdx.x, t = threadIdx.x;
    const int ci = t & 31, seg = t >> 5;
    constexpr int PER = NPART / 8;
    __shared__ float red[3][8][33];

    float M = -1e30f;
    for (int k = 0; k < PER; ++k)
        M = fmaxf(M, pm[((size_t)b * NPART + seg * PER + k) * 32 + ci]);
    red[0][seg][ci] = M;
    __syncthreads();
    float Mg = red[0][0][ci];
#pragma unroll
    for (int q = 1; q < 8; ++q) Mg = fmaxf(Mg, red[0][q][ci]);

    float Z = 0.0f, T = 0.0f;
    for (int k = 0; k < PER; ++k) {
        const size_t i = ((size_t)b * NPART + seg * PER + k) * 32 + ci;
        const float dm = pm[i] - Mg;
        const float e = __expf(dm);
        Z += ps[i] * e;
        if constexpr (ENT) T += (pt[i] + ps[i] * dm) * e;
    }
    red[1][seg][ci] = Z;
    if constexpr (ENT) red[2][seg][ci] = T;
    __syncthreads();
    if (t < 32) {
        float Zt = 0.0f, Tt = 0.0f;
#pragma unroll
        for (int q = 0; q < 8; ++q) {
            Zt += red[1][q][ci];
            if constexpr (ENT) Tt += red[2][q][ci];
        }
        sm[b * 32 + ci] = Mg;
        siz[b * 32 + ci] = 1.0f / Zt;
        if constexpr (ENT)   // ent = (lnZ - T/Z)/ln(32768); eps-in-log ~3e-5
            entp[b * 32 + ci] = (logf(Zt) - Tt / Zt) * (1.0f / 10.39720770839918f);
    }
}

// ---------------------------------------------------------------------------
extern "C" void kernel_launch(void* const* d_in, const int* in_sizes, int n_in,
                              void* d_out, int out_size, void* d_ws, size_t ws_size,
                              hipStream_t stream) {
    const float* in = (const float*)d_in[0];   // (8,32,8,32,32)
    const float* cw = (const float*)d_in[1];   // (128,1,3,3,3)
    const float* cb = (const float*)d_in[2];   // (128,)
    float* out = (float*)d_out;                // 1048576 + 1 floats

    unsigned* Bpk = (unsigned*)d_ws;           // 16 MiB
    float* pm0  = (float*)(Bpk + 4194304);     // [2048*32] each
    float* ps0  = pm0 + 65536;
    float* pm1  = ps0 + 65536;
    float* ps1  = pm1 + 65536;
    float* pt1  = ps1 + 65536;
    float* sm0  = pt1 + 65536;                 // [256] each
    float* siz0 = sm0 + 256;
    float* sm1  = siz0 + 256;
    float* siz1 = sm1 + 256;
    float* entp = siz1 + 256;
    unsigned short* wg = (unsigned short*)(entp + 256);   // 3712 u16

    k_caps<0><<<2048, 256, 0, stream>>>(in, cw, wg, cb, Bpk,
                                        nullptr, nullptr, pm0, ps0, pt1, out);
    k_comb<256, false><<<8, 256, 0, stream>>>(pm0, ps0, nullptr, sm0, siz0, nullptr);
    k_caps<1><<<2048, 256, 0, stream>>>(in, cw, wg, cb, Bpk,
                                        sm0, siz0, pm1, ps1, pt1, out);
    k_comb<256, true><<<8, 256, 0, stream>>>(pm1, ps1, pt1, sm1, siz1, entp);
    k_caps<2><<<2048, 256, 0, stream>>>(in, cw, wg, cb, Bpk,
                                        sm1, siz1, pm1, ps1, entp, out);
}